// Round 4
// baseline (2394.334 us; speedup 1.0000x reference)
//
#include <hip/hip_runtime.h>
#include <stdint.h>

#define TSTEPS 1000
#define NB 256
#define NF 64
#define NH 256   // H1 == H2 == 256

// Prep: W2T[h1][h2] = W2[h2][h1] for h1<256, plus an all-zero sentinel row at
// h1=256 (gather padding; adding +0.0f is a bitwise no-op). Zero counters.
__global__ void snn_prep(const float* __restrict__ W2, float* __restrict__ W2T,
                         unsigned int* __restrict__ counts) {
    int idx = blockIdx.x * 256 + threadIdx.x;     // 0 .. 257*256-1
    if (idx < NH * NH)
        W2T[idx] = W2[(idx & 255) * 256 + (idx >> 8)];
    else
        W2T[idx] = 0.0f;                          // sentinel row h1 == 256
    if (idx < 2) counts[idx] = 0u;
}

// Main: IDENTICAL arithmetic to the round-1 kernel (which verified with
// absmax = 0.0). Only the load scheduling inside each step changed: gather
// indices are extracted first (scalar ops), all loads of a round are issued
// together (latency overlapped), then the accumulate chains run in exactly
// the same per-chain ascending order as round 1. Short chains are padded
// with sentinel zero rows: acc += 0.0f is bitwise identity (acc is never -0).
__launch_bounds__(256, 1)
__global__ void snn_main(const float* __restrict__ spikes,
                         const float* __restrict__ W1,
                         const float* __restrict__ b1,
                         const float* __restrict__ W2T,
                         const float* __restrict__ b2,
                         const float* __restrict__ Wr,
                         const float* __restrict__ br,
                         float* __restrict__ out,
                         unsigned int* __restrict__ counts) {
    const int b = blockIdx.x;
    const int h = threadIdx.x;
    const int lane = h & 63;
    const int wv = h >> 6;

    __shared__ float W1T[NF + 1][NH + 1];   // +1 row: sentinel zeros (f==64)
    __shared__ float xbuf[16 * NF];         // 16-step input chunk
    __shared__ unsigned char slist[2][256]; // per-wave compacted spk1 lists
    __shared__ int scnt[2][4];
    __shared__ float rp0[4], rp1[4];
    __shared__ int rc1[4], rc2[4];

    // stage W1 transposed: W1T[f][h1] = W1[h1*64+f]; plus sentinel row.
    // Visibility guaranteed by the t=0 xbuf staging __syncthreads below.
    for (int i = h; i < NH * NF; i += 256) {
        W1T[i & 63][i >> 6] = W1[i];
    }
    W1T[64][h] = 0.0f;

    const float b1h = b1[h];
    const float b2h = b2[h];
    float mem1 = 0.f, mem2 = 0.f, mem2s = 0.f;
    int cnt1 = 0, cnt2 = 0;

    for (int t = 0; t < TSTEPS; ++t) {
        if ((t & 15) == 0) {
            // stage next 16 input rows (16x64 floats), coalesced
            #pragma unroll
            for (int k = 0; k < 4; ++k) {
                int idx = k * 256 + h;
                int tt = idx >> 6, f = idx & 63;
                int tg = t + tt;
                xbuf[idx] = (tg < TSTEPS)
                    ? spikes[(size_t)tg * (NB * NF) + b * NF + f] : 0.f;
            }
            __syncthreads();   // also covers W1T staging at t==0
        }
        // input mask: every wave computes it redundantly -> wave-uniform SGPR
        float xv = xbuf[((t & 15) << 6) | lane];
        unsigned long long xmask = __ballot(xv > 0.f);

        // layer 1: same 4 chains over 16-feature subwords, ascending f,
        // combined ((a0+a1)+(a2+a3)) — bitwise identical to round 1.
        unsigned xm0 = (unsigned)(xmask & 0xFFFFull);
        unsigned xm1 = (unsigned)((xmask >> 16) & 0xFFFFull);
        unsigned xm2 = (unsigned)((xmask >> 32) & 0xFFFFull);
        unsigned xm3 = (unsigned)((xmask >> 48) & 0xFFFFull);
        float a0 = 0.f, a1 = 0.f, a2 = 0.f, a3 = 0.f;
        while (xm0 | xm1 | xm2 | xm3) {
            int f0[8], f1[8], f2[8], f3[8];
            #pragma unroll
            for (int j = 0; j < 8; ++j) {
                f0[j] = xm0 ? (int)__builtin_ctz(xm0)        : 64; xm0 &= xm0 - 1;
                f1[j] = xm1 ? (int)__builtin_ctz(xm1) + 16   : 64; xm1 &= xm1 - 1;
                f2[j] = xm2 ? (int)__builtin_ctz(xm2) + 32   : 64; xm2 &= xm2 - 1;
                f3[j] = xm3 ? (int)__builtin_ctz(xm3) + 48   : 64; xm3 &= xm3 - 1;
            }
            float v0[8], v1[8], v2[8], v3[8];
            #pragma unroll
            for (int j = 0; j < 8; ++j) {
                v0[j] = W1T[f0[j]][h];
                v1[j] = W1T[f1[j]][h];
                v2[j] = W1T[f2[j]][h];
                v3[j] = W1T[f3[j]][h];
            }
            #pragma unroll
            for (int j = 0; j < 8; ++j) a0 += v0[j];
            #pragma unroll
            for (int j = 0; j < 8; ++j) a1 += v1[j];
            #pragma unroll
            for (int j = 0; j < 8; ++j) a2 += v2[j];
            #pragma unroll
            for (int j = 0; j < 8; ++j) a3 += v3[j];
        }
        float cur1 = b1h + ((a0 + a1) + (a2 + a3));

        float reset1 = (mem1 > 1.f) ? 1.f : 0.f;
        mem1 = 0.8187307530779818f * mem1 + cur1 - reset1;   // beta1 = exp(-1/5)
        bool s1 = (mem1 - 1.f) > 0.f;
        cnt1 += (int)s1;

        // publish spk1 as compacted per-wave index lists (double-buffered)
        unsigned long long smask = __ballot(s1);
        int buf = t & 1;
        if (lane == 0) scnt[buf][wv] = __popcll(smask);
        if (s1) {
            int rank = __popcll(smask & ((1ull << lane) - 1ull));
            slist[buf][(wv << 6) + rank] = (unsigned char)h;
        }
        __syncthreads();   // single barrier per step

        // layer 2: same 4 chains (one per source wave list, ascending),
        // combined ((q0+q1)+(q2+q3)) — bitwise identical to round 1.
        int c0 = scnt[buf][0], c1 = scnt[buf][1];
        int c2 = scnt[buf][2], c3 = scnt[buf][3];
        int nmax = max(max(c0, c1), max(c2, c3));
        float q0 = 0.f, q1 = 0.f, q2 = 0.f, q3 = 0.f;
        const float* W2Th = W2T + h;
        const unsigned char* sl = slist[buf];
        for (int i = 0; i < nmax; i += 8) {
            int g0[8], g1[8], g2[8], g3[8];
            #pragma unroll
            for (int j = 0; j < 8; ++j) {
                int ij = i + j;
                g0[j] = (ij < c0) ? (int)sl[ij]       : 256;
                g1[j] = (ij < c1) ? (int)sl[64 + ij]  : 256;
                g2[j] = (ij < c2) ? (int)sl[128 + ij] : 256;
                g3[j] = (ij < c3) ? (int)sl[192 + ij] : 256;
            }
            float w0[8], w1[8], w2[8], w3[8];
            #pragma unroll
            for (int j = 0; j < 8; ++j) {
                w0[j] = W2Th[g0[j] << 8];
                w1[j] = W2Th[g1[j] << 8];
                w2[j] = W2Th[g2[j] << 8];
                w3[j] = W2Th[g3[j] << 8];
            }
            #pragma unroll
            for (int j = 0; j < 8; ++j) q0 += w0[j];
            #pragma unroll
            for (int j = 0; j < 8; ++j) q1 += w1[j];
            #pragma unroll
            for (int j = 0; j < 8; ++j) q2 += w2[j];
            #pragma unroll
            for (int j = 0; j < 8; ++j) q3 += w3[j];
        }
        float cur2 = b2h + ((q0 + q1) + (q2 + q3));

        float reset2 = (mem2 > 1.f) ? 1.f : 0.f;
        mem2 = 0.9048374180359595f * mem2 + cur2 - reset2;   // beta2 = exp(-1/10)
        bool s2 = (mem2 - 1.f) > 0.f;
        cnt2 += (int)s2;
        mem2s += mem2;
    }

    // readout: out[b,:] = (mem2_sum/T) @ Wr.T + br ; block-level reduction
    // (verbatim round-1 code)
    float v = mem2s / 1000.0f;
    float p0 = v * Wr[h];
    float p1 = v * Wr[NH + h];
    int rcs1 = cnt1, rcs2 = cnt2;
    for (int off = 32; off > 0; off >>= 1) {
        p0 += __shfl_down(p0, off);
        p1 += __shfl_down(p1, off);
        rcs1 += __shfl_down(rcs1, off);
        rcs2 += __shfl_down(rcs2, off);
    }
    if (lane == 0) { rp0[wv] = p0; rp1[wv] = p1; rc1[wv] = rcs1; rc2[wv] = rcs2; }
    __syncthreads();
    if (h == 0) {
        out[2 * b]     = ((rp0[0] + rp0[1]) + (rp0[2] + rp0[3])) + br[0];
        out[2 * b + 1] = ((rp1[0] + rp1[1]) + (rp1[2] + rp1[3])) + br[1];
        atomicAdd(&counts[0], (unsigned)(rc1[0] + rc1[1] + rc1[2] + rc1[3]));
        atomicAdd(&counts[1], (unsigned)(rc2[0] + rc2[1] + rc2[2] + rc2[3]));
    }
}

__global__ void snn_finalize(const unsigned int* __restrict__ counts,
                             float* __restrict__ out) {
    if (threadIdx.x < 2)
        out[512 + threadIdx.x] = (float)counts[threadIdx.x] / 65536000.0f; // T*B*256
}

extern "C" void kernel_launch(void* const* d_in, const int* in_sizes, int n_in,
                              void* d_out, int out_size, void* d_ws, size_t ws_size,
                              hipStream_t stream) {
    const float* spikes = (const float*)d_in[0];
    const float* W1     = (const float*)d_in[1];
    const float* b1     = (const float*)d_in[2];
    const float* W2     = (const float*)d_in[3];
    const float* b2     = (const float*)d_in[4];
    const float* Wr     = (const float*)d_in[5];
    const float* br     = (const float*)d_in[6];
    float* out = (float*)d_out;

    float* W2T = (float*)d_ws;                      // 257*256*4 = 263168 B
    unsigned int* counts = (unsigned int*)((char*)d_ws + 257 * 256 * sizeof(float));

    snn_prep<<<257, 256, 0, stream>>>(W2, W2T, counts);
    snn_main<<<256, 256, 0, stream>>>(spikes, W1, b1, W2T, b2, Wr, br, out, counts);
    snn_finalize<<<1, 64, 0, stream>>>(counts, out);
}

// Round 6
// 2264.572 us; speedup vs baseline: 1.0573x; 1.0573x over previous
//
#include <hip/hip_runtime.h>
#include <stdint.h>

typedef unsigned long long u64;

#define TSTEPS 1000
#define NB 256
#define NF 64
#define NH 256   // H1 == H2 == 256

// Prep: W2T[h1][h2] = W2[h2][h1] for h1<256, plus an all-zero sentinel row at
// h1=256 (gather padding; adding +0.0f is a bitwise no-op). Zero counters.
// (verbatim round-4, which passed with absmax 0.0)
__global__ void snn_prep(const float* __restrict__ W2, float* __restrict__ W2T,
                         unsigned int* __restrict__ counts) {
    int idx = blockIdx.x * 256 + threadIdx.x;     // 0 .. 257*256-1
    if (idx < NH * NH)
        W2T[idx] = W2[(idx & 255) * 256 + (idx >> 8)];
    else
        W2T[idx] = 0.0f;                          // sentinel row h1 == 256
    if (idx < 2) counts[idx] = 0u;
}

// Main: arithmetic is BITWISE IDENTICAL to round-4 (passed, absmax 0.0):
// same thread->h mapping, same 4 chains in the same ascending order, same
// 8-slot sentinel rounds, same combines, same recurrence statements, same
// readout. Only the instruction SCHEDULE changed: layer-2's first gather
// round for step t is issued before layer-1's (independent) work for step
// t+1, so the L2 load latency hides behind L1's LDS/VALU work instead of
// being serially exposed. Barrier structure per step is unchanged (one
// __syncthreads per step, one extra per 16-step staging).
__launch_bounds__(256, 1)
__global__ void snn_main(const float* __restrict__ spikes,
                         const float* __restrict__ W1,
                         const float* __restrict__ b1,
                         const float* __restrict__ W2T,
                         const float* __restrict__ b2,
                         const float* __restrict__ Wr,
                         const float* __restrict__ br,
                         float* __restrict__ out,
                         unsigned int* __restrict__ counts) {
    const int b = blockIdx.x;
    const int h = threadIdx.x;
    const int lane = h & 63;
    const int wv = h >> 6;

    __shared__ float W1T[NF + 1][NH + 1];   // +1 row: sentinel zeros (f==64)
    __shared__ float xbuf[16 * NF];         // 16-step input chunk
    __shared__ unsigned char slist[2][256]; // per-wave compacted spk1 lists
    __shared__ int scnt[2][4];
    __shared__ float rp0[4], rp1[4];
    __shared__ int rc1[4], rc2[4];

    // stage W1 transposed: W1T[f][h1] = W1[h1*64+f]; plus sentinel row.
    for (int i = h; i < NH * NF; i += 256) {
        W1T[i & 63][i >> 6] = W1[i];
    }
    W1T[64][h] = 0.0f;

    const float b1h = b1[h];
    const float b2h = b2[h];
    const float* W2Th = W2T + h;
    float mem1 = 0.f, mem2 = 0.f, mem2s = 0.f;
    int cnt1 = 0, cnt2 = 0;

    // stage 16 input rows starting at 'base' (float4, bit-identical values)
    auto stage16 = [&](int base) {
        int slot = h >> 4;            // 0..15
        int f4 = (h & 15) << 2;       // 0,4,..,60
        int tg = base + slot;
        float4 v = make_float4(0.f, 0.f, 0.f, 0.f);
        if (tg < TSTEPS)
            v = *(const float4*)(spikes + (size_t)tg * (NB * NF) + b * NF + f4);
        *(float4*)&xbuf[(slot << 6) | f4] = v;
    };

    // full layer-1 step for time u: cur1 chains (r4 verbatim), mem1 update,
    // publish spk1 list into buffer u&1. No barrier inside.
    auto l1_step = [&](int u) {
        float xv = xbuf[((u & 15) << 6) | lane];
        u64 xmask = __ballot(xv > 0.f);
        unsigned xm0 = (unsigned)(xmask & 0xFFFFull);
        unsigned xm1 = (unsigned)((xmask >> 16) & 0xFFFFull);
        unsigned xm2 = (unsigned)((xmask >> 32) & 0xFFFFull);
        unsigned xm3 = (unsigned)((xmask >> 48) & 0xFFFFull);
        float a0 = 0.f, a1 = 0.f, a2 = 0.f, a3 = 0.f;
        while (xm0 | xm1 | xm2 | xm3) {
            int f0[8], f1[8], f2[8], f3[8];
            #pragma unroll
            for (int j = 0; j < 8; ++j) {
                f0[j] = xm0 ? (int)__builtin_ctz(xm0)      : 64; xm0 &= xm0 - 1;
                f1[j] = xm1 ? (int)__builtin_ctz(xm1) + 16 : 64; xm1 &= xm1 - 1;
                f2[j] = xm2 ? (int)__builtin_ctz(xm2) + 32 : 64; xm2 &= xm2 - 1;
                f3[j] = xm3 ? (int)__builtin_ctz(xm3) + 48 : 64; xm3 &= xm3 - 1;
            }
            float v0[8], v1[8], v2[8], v3[8];
            #pragma unroll
            for (int j = 0; j < 8; ++j) {
                v0[j] = W1T[f0[j]][h];
                v1[j] = W1T[f1[j]][h];
                v2[j] = W1T[f2[j]][h];
                v3[j] = W1T[f3[j]][h];
            }
            #pragma unroll
            for (int j = 0; j < 8; ++j) a0 += v0[j];
            #pragma unroll
            for (int j = 0; j < 8; ++j) a1 += v1[j];
            #pragma unroll
            for (int j = 0; j < 8; ++j) a2 += v2[j];
            #pragma unroll
            for (int j = 0; j < 8; ++j) a3 += v3[j];
        }
        float cur1 = b1h + ((a0 + a1) + (a2 + a3));
        float reset1 = (mem1 > 1.f) ? 1.f : 0.f;
        mem1 = 0.8187307530779818f * mem1 + cur1 - reset1;   // beta1 = exp(-1/5)
        bool s1 = (mem1 - 1.f) > 0.f;
        cnt1 += (int)s1;
        u64 smv = __ballot(s1);
        int pb = u & 1;
        if (lane == 0) scnt[pb][wv] = __popcll(smv);
        if (s1) {
            int rank = __popcll(smv & ((1ull << lane) - 1ull));
            slist[pb][(wv << 6) + rank] = (unsigned char)h;
        }
    };

    // prologue: stage steps 0..15, then layer-1 of step 0, publish its list
    stage16(0);
    __syncthreads();        // covers W1T staging + xbuf
    l1_step(0);
    __syncthreads();        // publish slist[0] for t=0

    for (int t = 0; t < TSTEPS; ++t) {
        const bool do_l1 = (t < TSTEPS - 1);
        // restage input chunk when step t+1 rolls over a 16-boundary
        if (do_l1 && (((t + 1) & 15) == 0)) {
            stage16(t + 1);
            __syncthreads();   // publish xbuf before ballots (r4-equivalent)
        }

        // ---- layer 2, step t: extract round 0 and ISSUE its loads early.
        // Predicated sentinel slots (g=256 -> zero row) add +0.0f, which is
        // bitwise identity — identical chain values to r4.
        int buf = t & 1;
        int c0 = scnt[buf][0], c1 = scnt[buf][1];
        int c2 = scnt[buf][2], c3 = scnt[buf][3];
        int nmax = max(max(c0, c1), max(c2, c3));
        const unsigned char* sl = slist[buf];
        int g0[8], g1[8], g2[8], g3[8];
        #pragma unroll
        for (int j = 0; j < 8; ++j) {
            g0[j] = (j < c0) ? (int)sl[j]       : 256;
            g1[j] = (j < c1) ? (int)sl[64 + j]  : 256;
            g2[j] = (j < c2) ? (int)sl[128 + j] : 256;
            g3[j] = (j < c3) ? (int)sl[192 + j] : 256;
        }
        float w0[8], w1[8], w2[8], w3[8];
        #pragma unroll
        for (int j = 0; j < 8; ++j) {
            w0[j] = W2Th[g0[j] << 8];
            w1[j] = W2Th[g1[j] << 8];
            w2[j] = W2Th[g2[j] << 8];
            w3[j] = W2Th[g3[j] << 8];
        }

        // ---- layer 1, step t+1 (independent of layer 2 of step t):
        // runs while the round-0 loads are in flight.
        if (do_l1) l1_step(t + 1);

        // ---- layer 2, step t: consume round 0 in r4's exact order,
        // then the (rare) remaining rounds, then the recurrence.
        float q0 = 0.f, q1 = 0.f, q2 = 0.f, q3 = 0.f;
        #pragma unroll
        for (int j = 0; j < 8; ++j) q0 += w0[j];
        #pragma unroll
        for (int j = 0; j < 8; ++j) q1 += w1[j];
        #pragma unroll
        for (int j = 0; j < 8; ++j) q2 += w2[j];
        #pragma unroll
        for (int j = 0; j < 8; ++j) q3 += w3[j];
        for (int i = 8; i < nmax; i += 8) {
            int e0[8], e1[8], e2[8], e3[8];
            #pragma unroll
            for (int j = 0; j < 8; ++j) {
                int ij = i + j;
                e0[j] = (ij < c0) ? (int)sl[ij]       : 256;
                e1[j] = (ij < c1) ? (int)sl[64 + ij]  : 256;
                e2[j] = (ij < c2) ? (int)sl[128 + ij] : 256;
                e3[j] = (ij < c3) ? (int)sl[192 + ij] : 256;
            }
            float y0[8], y1[8], y2[8], y3[8];
            #pragma unroll
            for (int j = 0; j < 8; ++j) {
                y0[j] = W2Th[e0[j] << 8];
                y1[j] = W2Th[e1[j] << 8];
                y2[j] = W2Th[e2[j] << 8];
                y3[j] = W2Th[e3[j] << 8];
            }
            #pragma unroll
            for (int j = 0; j < 8; ++j) q0 += y0[j];
            #pragma unroll
            for (int j = 0; j < 8; ++j) q1 += y1[j];
            #pragma unroll
            for (int j = 0; j < 8; ++j) q2 += y2[j];
            #pragma unroll
            for (int j = 0; j < 8; ++j) q3 += y3[j];
        }
        float cur2 = b2h + ((q0 + q1) + (q2 + q3));

        float reset2 = (mem2 > 1.f) ? 1.f : 0.f;
        mem2 = 0.9048374180359595f * mem2 + cur2 - reset2;   // beta2 = exp(-1/10)
        bool s2 = (mem2 - 1.f) > 0.f;
        cnt2 += (int)s2;
        mem2s += mem2;

        __syncthreads();   // publish slist[(t+1)&1]; protect double-buffer
    }

    // readout + stats: verbatim round-4 (passed at absmax 0.0)
    float v = mem2s / 1000.0f;
    float p0 = v * Wr[h];
    float p1 = v * Wr[NH + h];
    int rcs1 = cnt1, rcs2 = cnt2;
    for (int off = 32; off > 0; off >>= 1) {
        p0 += __shfl_down(p0, off);
        p1 += __shfl_down(p1, off);
        rcs1 += __shfl_down(rcs1, off);
        rcs2 += __shfl_down(rcs2, off);
    }
    if (lane == 0) { rp0[wv] = p0; rp1[wv] = p1; rc1[wv] = rcs1; rc2[wv] = rcs2; }
    __syncthreads();
    if (h == 0) {
        out[2 * b]     = ((rp0[0] + rp0[1]) + (rp0[2] + rp0[3])) + br[0];
        out[2 * b + 1] = ((rp1[0] + rp1[1]) + (rp1[2] + rp1[3])) + br[1];
        atomicAdd(&counts[0], (unsigned)(rc1[0] + rc1[1] + rc1[2] + rc1[3]));
        atomicAdd(&counts[1], (unsigned)(rc2[0] + rc2[1] + rc2[2] + rc2[3]));
    }
}

__global__ void snn_finalize(const unsigned int* __restrict__ counts,
                             float* __restrict__ out) {
    if (threadIdx.x < 2)
        out[512 + threadIdx.x] = (float)counts[threadIdx.x] / 65536000.0f; // T*B*256
}

extern "C" void kernel_launch(void* const* d_in, const int* in_sizes, int n_in,
                              void* d_out, int out_size, void* d_ws, size_t ws_size,
                              hipStream_t stream) {
    const float* spikes = (const float*)d_in[0];
    const float* W1     = (const float*)d_in[1];
    const float* b1     = (const float*)d_in[2];
    const float* W2     = (const float*)d_in[3];
    const float* b2     = (const float*)d_in[4];
    const float* Wr     = (const float*)d_in[5];
    const float* br     = (const float*)d_in[6];
    float* out = (float*)d_out;

    float* W2T = (float*)d_ws;                      // 257*256*4 = 263168 B
    unsigned int* counts = (unsigned int*)((char*)d_ws + 257 * 256 * sizeof(float));

    snn_prep<<<257, 256, 0, stream>>>(W2, W2T, counts);
    snn_main<<<256, 256, 0, stream>>>(spikes, W1, b1, W2T, b2, Wr, br, out, counts);
    snn_finalize<<<1, 64, 0, stream>>>(counts, out);
}